// Round 1
// baseline (506.918 us; speedup 1.0000x reference)
//
#include <hip/hip_runtime.h>

#define BB 8
#define NN 1024
#define CC 384
#define HH 6
#define HD 64
#define SCALE 0.125f
#define EPSV 1e-5f

// ---------------------------------------------------------------------------
// LDS tile loaders. dst is flat float* with row stride 68 (padded).
// Transposed: dst[k*68 + r] = src[r*ld + k]   (K-dim becomes LDS row)
// Natural:    dst[r*68 + k] = src[r*ld + k]
// ---------------------------------------------------------------------------
template<int NROW, int NK4>
__device__ inline void load_T(float* dst, const float* __restrict__ src, int ld, int tid) {
    constexpr int TOTAL = NROW * NK4;   // float4 count
#pragma unroll
    for (int it = 0; it < TOTAL / 256; ++it) {
        int idx = tid + it * 256;
        int r = idx / NK4;
        int k4 = idx % NK4;
        float4 val = *(const float4*)&src[(size_t)r * ld + k4 * 4];
        dst[(k4 * 4 + 0) * 68 + r] = val.x;
        dst[(k4 * 4 + 1) * 68 + r] = val.y;
        dst[(k4 * 4 + 2) * 68 + r] = val.z;
        dst[(k4 * 4 + 3) * 68 + r] = val.w;
    }
}

template<int NROW, int NK4>
__device__ inline void load_N(float* dst, const float* __restrict__ src, int ld, int tid) {
    constexpr int TOTAL = NROW * NK4;
#pragma unroll
    for (int it = 0; it < TOTAL / 256; ++it) {
        int idx = tid + it * 256;
        int r = idx / NK4;
        int k4 = idx % NK4;
        *(float4*)&dst[r * 68 + k4 * 4] = *(const float4*)&src[(size_t)r * ld + k4 * 4];
    }
}

__device__ inline void fma16(float acc[4][4], float4 a4, float4 b4) {
    float av[4] = {a4.x, a4.y, a4.z, a4.w};
    float bv[4] = {b4.x, b4.y, b4.z, b4.w};
#pragma unroll
    for (int i = 0; i < 4; ++i)
#pragma unroll
        for (int j = 0; j < 4; ++j)
            acc[i][j] = fmaf(av[i], bv[j], acc[i][j]);
}

// ---------------------------------------------------------------------------
// Kernel 1: qkv = x @ Wqkv^T, scattered to q/k/v in [B,H,N,HD] layout.
// grid (8192/64, 1152/64), block 256.
// ---------------------------------------------------------------------------
__global__ __launch_bounds__(256) void qkv_gemm(const float* __restrict__ x,
                                                const float* __restrict__ w,
                                                float* __restrict__ q,
                                                float* __restrict__ k,
                                                float* __restrict__ v) {
    __shared__ float sA[32 * 68];
    __shared__ float sB[32 * 68];
    const int tid = threadIdx.x;
    const int tx = tid & 15, ty = tid >> 4;
    const int m0 = blockIdx.x * 64;
    const int j0 = blockIdx.y * 64;

    float acc[4][4] = {};
    for (int k0 = 0; k0 < CC; k0 += 32) {
        load_T<64, 8>(sA, x + (size_t)m0 * CC + k0, CC, tid);
        load_T<64, 8>(sB, w + (size_t)j0 * CC + k0, CC, tid);
        __syncthreads();
#pragma unroll
        for (int kk = 0; kk < 32; ++kk) {
            float4 a = *(const float4*)&sA[kk * 68 + ty * 4];
            float4 b = *(const float4*)&sB[kk * 68 + tx * 4];
            fma16(acc, a, b);
        }
        __syncthreads();
    }
    // j0 is a multiple of 64 -> whole tile is one (three, h)
    const int three = j0 / CC;            // 0,1,2
    const int h     = (j0 % CC) / HD;
    float* dst = (three == 0) ? q : ((three == 1) ? k : v);
    const int b = m0 / NN;                // 64 | 1024 -> constant over tile
#pragma unroll
    for (int i = 0; i < 4; ++i) {
        const int n = (m0 + ty * 4 + i) % NN;
        float4 o = {acc[i][0], acc[i][1], acc[i][2], acc[i][3]};
        *(float4*)&dst[(((size_t)b * HH + h) * NN + n) * HD + tx * 4] = o;
    }
}

// ---------------------------------------------------------------------------
// Kernel 2: G[bh][d1][d2] = sum_n K[bh][n][d1] * V[bh][n][d2].  grid 48.
// ---------------------------------------------------------------------------
__global__ __launch_bounds__(256) void ktv_kernel(const float* __restrict__ k,
                                                  const float* __restrict__ v,
                                                  float* __restrict__ g) {
    __shared__ float sK[64 * 68];
    __shared__ float sV[64 * 68];
    const int tid = threadIdx.x;
    const int tx = tid & 15, ty = tid >> 4;
    const int bh = blockIdx.x;
    const float* kp = k + (size_t)bh * NN * HD;
    const float* vp = v + (size_t)bh * NN * HD;

    float acc[4][4] = {};
    for (int n0 = 0; n0 < NN; n0 += 64) {
        load_N<64, 16>(sK, kp + (size_t)n0 * HD, HD, tid);
        load_N<64, 16>(sV, vp + (size_t)n0 * HD, HD, tid);
        __syncthreads();
#pragma unroll
        for (int nn = 0; nn < 64; ++nn) {
            float4 a = *(const float4*)&sK[nn * 68 + ty * 4];
            float4 b = *(const float4*)&sV[nn * 68 + tx * 4];
            fma16(acc, a, b);
        }
        __syncthreads();
    }
#pragma unroll
    for (int i = 0; i < 4; ++i) {
        float4 o = {acc[i][0], acc[i][1], acc[i][2], acc[i][3]};
        *(float4*)&g[(size_t)bh * HD * HD + (ty * 4 + i) * HD + tx * 4] = o;
    }
}

// ---------------------------------------------------------------------------
// Kernel 3: fused relu-attention.
//   out = alpha * (relu(S)@V)/(rowsum+eps) + (1-alpha)*(scale/N)*(Q@G)
// grid (N/64, B*H), block 256.
// ---------------------------------------------------------------------------
__global__ __launch_bounds__(256) void attn_kernel(const float* __restrict__ q,
                                                   const float* __restrict__ k,
                                                   const float* __restrict__ v,
                                                   const float* __restrict__ g,
                                                   const float* __restrict__ alpha,
                                                   float* __restrict__ aout) {
    __shared__ float sQT[64 * 68];   // [d][r]
    __shared__ float sKT[64 * 68];   // [d][c]; reused for G [k][d] after loop
    __shared__ float sV [64 * 68];   // [n][d]
    __shared__ float sPT[64 * 68];   // [c][r]; reused as reduction scratch
    __shared__ float rowsum[64];
    const int tid = threadIdx.x;
    const int tx = tid & 15, ty = tid >> 4;
    const int bh = blockIdx.y;
    const int h = bh % HH, b = bh / HH;
    const int n0 = blockIdx.x * 64;
    const float* qp = q + ((size_t)bh * NN + n0) * HD;
    const float* kp = k + (size_t)bh * NN * HD;
    const float* vp = v + (size_t)bh * NN * HD;

    load_T<64, 16>(sQT, qp, HD, tid);

    float acc1[4][4] = {};
    float accG[4][4] = {};
    float rs[4] = {};

    for (int k0 = 0; k0 < NN; k0 += 64) {
        __syncthreads();   // previous iter's reads of sKT/sV/sPT done
        load_T<64, 16>(sKT, kp + (size_t)k0 * HD, HD, tid);
        load_N<64, 16>(sV,  vp + (size_t)k0 * HD, HD, tid);
        __syncthreads();

        float s[4][4] = {};
#pragma unroll
        for (int dd = 0; dd < 64; ++dd) {
            float4 a = *(const float4*)&sQT[dd * 68 + ty * 4];
            float4 bq = *(const float4*)&sKT[dd * 68 + tx * 4];
            fma16(s, a, bq);
        }
#pragma unroll
        for (int i = 0; i < 4; ++i)
#pragma unroll
            for (int j = 0; j < 4; ++j) {
                float p = fmaxf(s[i][j] * SCALE, 0.f);
                rs[i] += p;
                sPT[(tx * 4 + j) * 68 + (ty * 4 + i)] = p;
            }
        __syncthreads();
#pragma unroll
        for (int kk = 0; kk < 64; ++kk) {
            float4 a = *(const float4*)&sPT[kk * 68 + ty * 4];
            float4 bv = *(const float4*)&sV[kk * 68 + tx * 4];
            fma16(acc1, a, bv);
        }
    }
    __syncthreads();   // everyone done reading sKT/sPT before reuse

    // G (natural [k][d]) into sKT; rowsum partials into sPT scratch
    load_N<64, 16>(sKT, g + (size_t)bh * HD * HD, HD, tid);
#pragma unroll
    for (int i = 0; i < 4; ++i)
        sPT[(ty * 4 + i) * 17 + tx] = rs[i];
    __syncthreads();

    if (tid < 64) {
        float ssum = 0.f;
#pragma unroll
        for (int t = 0; t < 16; ++t) ssum += sPT[tid * 17 + t];
        rowsum[tid] = ssum;
    }
#pragma unroll
    for (int kk = 0; kk < 64; ++kk) {
        float4 a = *(const float4*)&sQT[kk * 68 + ty * 4];
        float4 bg = *(const float4*)&sKT[kk * 68 + tx * 4];
        fma16(accG, a, bg);
    }
    __syncthreads();   // rowsum visible

    const float al = alpha[h];
    const float cg = (1.f - al) * (SCALE / (float)NN);
#pragma unroll
    for (int i = 0; i < 4; ++i) {
        const float inv = al / (rowsum[ty * 4 + i] + EPSV);
        const int n = n0 + ty * 4 + i;
        float4 o;
        o.x = acc1[i][0] * inv + cg * accG[i][0];
        o.y = acc1[i][1] * inv + cg * accG[i][1];
        o.z = acc1[i][2] * inv + cg * accG[i][2];
        o.w = acc1[i][3] * inv + cg * accG[i][3];
        *(float4*)&aout[((size_t)b * NN + n) * CC + h * HD + tx * 4] = o;
    }
}

// ---------------------------------------------------------------------------
// Kernel 4: out = attn_out @ Wproj^T + bproj.  grid (8192/64, 384/64).
// ---------------------------------------------------------------------------
__global__ __launch_bounds__(256) void proj_gemm(const float* __restrict__ a,
                                                 const float* __restrict__ w,
                                                 const float* __restrict__ bias,
                                                 float* __restrict__ out) {
    __shared__ float sA[32 * 68];
    __shared__ float sB[32 * 68];
    const int tid = threadIdx.x;
    const int tx = tid & 15, ty = tid >> 4;
    const int m0 = blockIdx.x * 64;
    const int j0 = blockIdx.y * 64;

    float acc[4][4] = {};
    for (int k0 = 0; k0 < CC; k0 += 32) {
        load_T<64, 8>(sA, a + (size_t)m0 * CC + k0, CC, tid);
        load_T<64, 8>(sB, w + (size_t)j0 * CC + k0, CC, tid);
        __syncthreads();
#pragma unroll
        for (int kk = 0; kk < 32; ++kk) {
            float4 a4 = *(const float4*)&sA[kk * 68 + ty * 4];
            float4 b4 = *(const float4*)&sB[kk * 68 + tx * 4];
            fma16(acc, a4, b4);
        }
        __syncthreads();
    }
    const float4 bb = *(const float4*)&bias[j0 + tx * 4];
#pragma unroll
    for (int i = 0; i < 4; ++i) {
        const int m = m0 + ty * 4 + i;
        float4 o;
        o.x = acc[i][0] + bb.x;
        o.y = acc[i][1] + bb.y;
        o.z = acc[i][2] + bb.z;
        o.w = acc[i][3] + bb.w;
        *(float4*)&out[(size_t)m * CC + j0 + tx * 4] = o;
    }
}

// ---------------------------------------------------------------------------
extern "C" void kernel_launch(void* const* d_in, const int* in_sizes, int n_in,
                              void* d_out, int out_size, void* d_ws, size_t ws_size,
                              hipStream_t stream) {
    const float* x     = (const float*)d_in[0];
    const float* Wqkv  = (const float*)d_in[1];
    const float* Wproj = (const float*)d_in[2];
    const float* bproj = (const float*)d_in[3];
    const float* alpha = (const float*)d_in[4];
    float* out = (float*)d_out;

    float* ws = (float*)d_ws;
    const size_t qkv_elems = (size_t)BB * HH * NN * HD;   // 3,145,728
    float* q = ws;
    float* k = q + qkv_elems;
    float* v = k + qkv_elems;
    float* g = v + qkv_elems;                              // 48*64*64
    float* aout = g + (size_t)BB * HH * HD * HD;

    qkv_gemm<<<dim3(128, 18), 256, 0, stream>>>(x, Wqkv, q, k, v);
    ktv_kernel<<<48, 256, 0, stream>>>(k, v, g);
    attn_kernel<<<dim3(16, 48), 256, 0, stream>>>(q, k, v, g, alpha, aout);
    proj_gemm<<<dim3(128, 6), 256, 0, stream>>>(aout, Wproj, bproj, out);
}

// Round 2
// 202.432 us; speedup vs baseline: 2.5041x; 2.5041x over previous
//
#include <hip/hip_runtime.h>
#include <stdint.h>

typedef _Float16 f16;
typedef _Float16 half8 __attribute__((ext_vector_type(8)));
typedef float f32x4 __attribute__((ext_vector_type(4)));

#define MFMA16(A, B, C) __builtin_amdgcn_mfma_f32_16x16x32_f16(A, B, C, 0, 0, 0)

#define GLOAD16(g, l) __builtin_amdgcn_global_load_lds( \
    (const __attribute__((address_space(1))) uint32_t*)(g), \
    (__attribute__((address_space(3))) uint32_t*)(l), 16, 0, 0)

__device__ inline void split2(float x, f16& h, f16& l) {
    h = (f16)x;
    l = (f16)(x - (float)h);
}

__device__ inline uint32_t packh(f16 a, f16 b) {
    union { f16 h[2]; uint32_t u; } t;
    t.h[0] = a; t.h[1] = b;
    return t.u;
}

// ---------------------------------------------------------------------------
// Convert fp32 array -> f16 hi/lo split arrays (vectorized x4).
// ---------------------------------------------------------------------------
__global__ void convert_split(const float* __restrict__ src, f16* __restrict__ hi,
                              f16* __restrict__ lo, int n4) {
    for (int i = blockIdx.x * blockDim.x + threadIdx.x; i < n4;
         i += gridDim.x * blockDim.x) {
        float4 v = ((const float4*)src)[i];
        float vv[4] = {v.x, v.y, v.z, v.w};
        union { f16 x[4]; uint2 u; } H, L;
#pragma unroll
        for (int j = 0; j < 4; ++j) {
            f16 hh = (f16)vv[j];
            H.x[j] = hh;
            L.x[j] = (f16)(vv[j] - (float)hh);
        }
        ((uint2*)hi)[i] = H.u;
        ((uint2*)lo)[i] = L.u;
    }
}

// ---------------------------------------------------------------------------
// Kernel 1: qkv = x @ Wqkv^T (f16-split MFMA). 128x128 tile, BK=32.
// Outputs: q (scaled by 0.125), k in [bh][n][64]; v TRANSPOSED [bh][64][1024].
// grid (64, 9), block 256.
// ---------------------------------------------------------------------------
__global__ __launch_bounds__(256) void qkv_gemm(
    const f16* __restrict__ xh, const f16* __restrict__ xl,
    const f16* __restrict__ wh, const f16* __restrict__ wl,
    f16* __restrict__ qh_, f16* __restrict__ ql_,
    f16* __restrict__ kh_, f16* __restrict__ kl_,
    f16* __restrict__ vth_, f16* __restrict__ vtl_) {
    __shared__ f16 sAh[128 * 32], sAl[128 * 32], sBh[128 * 32], sBl[128 * 32];
    const int tid = threadIdx.x;
    const int w = tid >> 6, lane = tid & 63;
    const int g = lane >> 4, q = lane & 15;
    const int m0 = blockIdx.x * 128, j0 = blockIdx.y * 128;
    const int wm = (w >> 1) * 64, wn = (w & 1) * 64;

    // each wave stages one LDS array
    const char* gb;
    f16* ld;
    if (w == 0)      { gb = (const char*)xh + (size_t)m0 * 768; ld = sAh; }
    else if (w == 1) { gb = (const char*)xl + (size_t)m0 * 768; ld = sAl; }
    else if (w == 2) { gb = (const char*)wh + (size_t)j0 * 768; ld = sBh; }
    else             { gb = (const char*)wl + (size_t)j0 * 768; ld = sBl; }

    f32x4 acc[4][4];
#pragma unroll
    for (int i = 0; i < 4; ++i)
#pragma unroll
        for (int j = 0; j < 4; ++j) acc[i][j] = (f32x4){0.f, 0.f, 0.f, 0.f};

    for (int ks = 0; ks < 12; ++ks) {
        const char* gk = gb + ks * 64;  // k0*2 bytes
#pragma unroll
        for (int i = 0; i < 8; ++i) {
            const int row = i * 16 + (lane >> 2);
            GLOAD16(gk + (size_t)row * 768 + (((lane & 3) ^ ((row & 6) >> 1)) << 4),
                    ld + i * 512);
        }
        __syncthreads();

        half8 am_h[4], am_l[4], bn_h[4], bn_l[4];
#pragma unroll
        for (int mi = 0; mi < 4; ++mi) {
            const int row = wm + 16 * mi + q;
            const int ch = (g ^ ((row & 6) >> 1)) * 8;
            am_h[mi] = *(const half8*)&sAh[row * 32 + ch];
            am_l[mi] = *(const half8*)&sAl[row * 32 + ch];
        }
#pragma unroll
        for (int nj = 0; nj < 4; ++nj) {
            const int row = wn + 16 * nj + q;
            const int ch = (g ^ ((row & 6) >> 1)) * 8;
            bn_h[nj] = *(const half8*)&sBh[row * 32 + ch];
            bn_l[nj] = *(const half8*)&sBl[row * 32 + ch];
        }
#pragma unroll
        for (int mi = 0; mi < 4; ++mi)
#pragma unroll
            for (int nj = 0; nj < 4; ++nj) {
                acc[mi][nj] = MFMA16(am_h[mi], bn_h[nj], acc[mi][nj]);
                acc[mi][nj] = MFMA16(am_h[mi], bn_l[nj], acc[mi][nj]);
                acc[mi][nj] = MFMA16(am_l[mi], bn_h[nj], acc[mi][nj]);
            }
        __syncthreads();
    }

    // epilogue: split + scatter to q/k (normal) or v (transposed)
#pragma unroll
    for (int nj = 0; nj < 4; ++nj) {
        const int jc = j0 + wn + 16 * nj + q;  // 0..1151
        const int t = jc / 384;
        const int rem = jc - t * 384;
        const int h = rem >> 6, d = rem & 63;
#pragma unroll
        for (int mi = 0; mi < 4; ++mi) {
            const int mg = m0 + wm + 16 * mi + 4 * g;
            const int b = mg >> 10, n = mg & 1023;
            const size_t bh = (size_t)(b * 6 + h);
            if (t == 0) {
#pragma unroll
                for (int r = 0; r < 4; ++r) {
                    float val = acc[mi][nj][r] * 0.125f;  // fold attn scale into q
                    f16 hh, ll;
                    split2(val, hh, ll);
                    qh_[bh * 65536 + (size_t)(n + r) * 64 + d] = hh;
                    ql_[bh * 65536 + (size_t)(n + r) * 64 + d] = ll;
                }
            } else if (t == 1) {
#pragma unroll
                for (int r = 0; r < 4; ++r) {
                    f16 hh, ll;
                    split2(acc[mi][nj][r], hh, ll);
                    kh_[bh * 65536 + (size_t)(n + r) * 64 + d] = hh;
                    kl_[bh * 65536 + (size_t)(n + r) * 64 + d] = ll;
                }
            } else {
                union { f16 x[4]; uint2 u; } HV, LV;
#pragma unroll
                for (int r = 0; r < 4; ++r) split2(acc[mi][nj][r], HV.x[r], LV.x[r]);
                *(uint2*)&vth_[bh * 65536 + (size_t)d * 1024 + n] = HV.u;
                *(uint2*)&vtl_[bh * 65536 + (size_t)d * 1024 + n] = LV.u;
            }
        }
    }
}

// ---------------------------------------------------------------------------
// Kernel 2: fused relu-attention, all-MFMA, swapped-operand form.
//   S^T = K·Q^T (per 64-key tile), relu/rowsum lane-local, P redistributed
//   via shfl butterfly, out^T = V^T·P.  Linear branch (alpha != 1) guarded.
// grid (16, 48), block 256 (4 waves x 16 q-rows). LDS 32KB single-buffered.
// ---------------------------------------------------------------------------
__global__ __launch_bounds__(256) void attn_mfma(
    const f16* __restrict__ qh_, const f16* __restrict__ ql_,
    const f16* __restrict__ kh_, const f16* __restrict__ kl_,
    const f16* __restrict__ vth_, const f16* __restrict__ vtl_,
    const float* __restrict__ alpha,
    f16* __restrict__ aoh, f16* __restrict__ aol) {
    __shared__ f16 sKh[64 * 64], sKl[64 * 64], sVh[64 * 64], sVl[64 * 64];
    const int tid = threadIdx.x;
    const int w = tid >> 6, lane = tid & 63;
    const int g = lane >> 4, q = lane & 15;
    const int bh = blockIdx.y, h = bh % 6;
    const int n0 = blockIdx.x * 64;
    const float al = alpha[h];
    const float cg = (1.0f - al) * (1.0f / 1024.0f);
    const bool useLin = (cg != 0.0f);

    // Q fragments in registers (q-row = lane&15 of this wave's 16 rows)
    const size_t qbase = (size_t)bh * 65536 + (size_t)(n0 + 16 * w + q) * 64;
    half8 Qh[2], Ql[2];
    Qh[0] = *(const half8*)&qh_[qbase + g * 8];
    Qh[1] = *(const half8*)&qh_[qbase + 32 + g * 8];
    Ql[0] = *(const half8*)&ql_[qbase + g * 8];
    Ql[1] = *(const half8*)&ql_[qbase + 32 + g * 8];

    f32x4 accP[4], accS[4];
#pragma unroll
    for (int i = 0; i < 4; ++i) {
        accP[i] = (f32x4){0.f, 0.f, 0.f, 0.f};
        accS[i] = (f32x4){0.f, 0.f, 0.f, 0.f};
    }
    float rs = 0.f;

    const int rl8 = lane >> 3, cl8 = lane & 7;
    const size_t kbb = (size_t)bh * 131072;

    for (int kt = 0; kt < 16; ++kt) {
        // ---- stage K,V tiles (wave w stages rows 16w..16w+15 of each array)
        const size_t kb = kbb + (size_t)kt * 8192;
        const size_t vb = kbb + (size_t)kt * 128;
#pragma unroll
        for (int i2 = 0; i2 < 2; ++i2) {
            const int rloc = 16 * w + i2 * 8 + rl8;
            const int chs = (cl8 ^ (rloc & 7)) << 4;
            const int ldso = (16 * w + i2 * 8) * 64;
            GLOAD16((const char*)kh_ + kb + (size_t)rloc * 128 + chs, &sKh[ldso]);
            GLOAD16((const char*)kl_ + kb + (size_t)rloc * 128 + chs, &sKl[ldso]);
            GLOAD16((const char*)vth_ + vb + (size_t)rloc * 2048 + chs, &sVh[ldso]);
            GLOAD16((const char*)vtl_ + vb + (size_t)rloc * 2048 + chs, &sVl[ldso]);
        }
        __syncthreads();

        // ---- S^T = K·Q^T : D rows = keys 16s+4g+r, col = q
        f32x4 sacc[4];
#pragma unroll
        for (int s = 0; s < 4; ++s) {
            sacc[s] = (f32x4){0.f, 0.f, 0.f, 0.f};
            const int row = 16 * s + q;
#pragma unroll
            for (int k2 = 0; k2 < 2; ++k2) {
                const int ch = ((k2 * 4 + g) ^ (row & 7)) * 8;
                half8 kfh = *(const half8*)&sKh[row * 64 + ch];
                half8 kfl = *(const half8*)&sKl[row * 64 + ch];
                sacc[s] = MFMA16(kfh, Qh[k2], sacc[s]);
                sacc[s] = MFMA16(kfh, Ql[k2], sacc[s]);
                sacc[s] = MFMA16(kfl, Qh[k2], sacc[s]);
            }
        }

        // ---- relu + rowsum + split/pack (P = relu(S'), scale pre-folded)
        uint32_t pkh[4][2], pkl[4][2];
#pragma unroll
        for (int s = 0; s < 4; ++s) {
            float p0 = fmaxf(sacc[s][0], 0.f), p1 = fmaxf(sacc[s][1], 0.f);
            float p2 = fmaxf(sacc[s][2], 0.f), p3 = fmaxf(sacc[s][3], 0.f);
            rs += (p0 + p1) + (p2 + p3);
            f16 h0, h1, h2, h3, l0, l1, l2, l3;
            split2(p0, h0, l0); split2(p1, h1, l1);
            split2(p2, h2, l2); split2(p3, h3, l3);
            pkh[s][0] = packh(h0, h1); pkh[s][1] = packh(h2, h3);
            pkl[s][0] = packh(l0, l1); pkl[s][1] = packh(l2, l3);
        }

        // ---- redistribute P via shfl butterfly, out^T += V^T·P
#pragma unroll
        for (int t2 = 0; t2 < 2; ++t2) {
            union { uint32_t u[4]; half8 v; } fh, fl;
#pragma unroll
            for (int r = 0; r < 4; ++r) {
                const int srcl = ((2 * g + (r >> 1)) & 3) * 16 + q;
                uint32_t a0 = __shfl(pkh[2 * t2][r & 1], srcl, 64);
                uint32_t b0 = __shfl(pkh[2 * t2 + 1][r & 1], srcl, 64);
                fh.u[r] = (g < 2) ? a0 : b0;
                uint32_t c0 = __shfl(pkl[2 * t2][r & 1], srcl, 64);
                uint32_t d0 = __shfl(pkl[2 * t2 + 1][r & 1], srcl, 64);
                fl.u[r] = (g < 2) ? c0 : d0;
            }
#pragma unroll
            for (int ds = 0; ds < 4; ++ds) {
                const int row = 16 * ds + q;
                const int ch = ((t2 * 4 + g) ^ (row & 7)) * 8;
                half8 vfh = *(const half8*)&sVh[row * 64 + ch];
                half8 vfl = *(const half8*)&sVl[row * 64 + ch];
                accP[ds] = MFMA16(vfh, fh.v, accP[ds]);
                accP[ds] = MFMA16(vfh, fl.v, accP[ds]);
                accP[ds] = MFMA16(vfl, fh.v, accP[ds]);
            }
        }

        // ---- linear branch (only when alpha != 1): accS += S_raw-weighted V
        if (useLin) {
            uint32_t skh[4][2], skl[4][2];
#pragma unroll
            for (int s = 0; s < 4; ++s) {
                f16 h0, h1, h2, h3, l0, l1, l2, l3;
                split2(sacc[s][0], h0, l0); split2(sacc[s][1], h1, l1);
                split2(sacc[s][2], h2, l2); split2(sacc[s][3], h3, l3);
                skh[s][0] = packh(h0, h1); skh[s][1] = packh(h2, h3);
                skl[s][0] = packh(l0, l1); skl[s][1] = packh(l2, l3);
            }
#pragma unroll
            for (int t2 = 0; t2 < 2; ++t2) {
                union { uint32_t u[4]; half8 v; } fh, fl;
#pragma unroll
                for (int r = 0; r < 4; ++r) {
                    const int srcl = ((2 * g + (r >> 1)) & 3) * 16 + q;
                    uint32_t a0 = __shfl(skh[2 * t2][r & 1], srcl, 64);
                    uint32_t b0 = __shfl(skh[2 * t2 + 1][r & 1], srcl, 64);
                    fh.u[r] = (g < 2) ? a0 : b0;
                    uint32_t c0 = __shfl(skl[2 * t2][r & 1], srcl, 64);
                    uint32_t d0 = __shfl(skl[2 * t2 + 1][r & 1], srcl, 64);
                    fl.u[r] = (g < 2) ? c0 : d0;
                }
#pragma unroll
                for (int ds = 0; ds < 4; ++ds) {
                    const int row = 16 * ds + q;
                    const int ch = ((t2 * 4 + g) ^ (row & 7)) * 8;
                    half8 vfh = *(const half8*)&sVh[row * 64 + ch];
                    half8 vfl = *(const half8*)&sVl[row * 64 + ch];
                    accS[ds] = MFMA16(vfh, fh.v, accS[ds]);
                    accS[ds] = MFMA16(vfh, fl.v, accS[ds]);
                    accS[ds] = MFMA16(vfl, fh.v, accS[ds]);
                }
            }
        }
        __syncthreads();
    }

    // rowsum across the 4 lane groups holding col q
    rs += __shfl_xor(rs, 16, 64);
    rs += __shfl_xor(rs, 32, 64);
    const float inv = al / (rs + 1e-5f);

    const int b = bh / 6;
    const size_t arow = (size_t)(b * 1024 + n0 + 16 * w + q) * 384 + h * 64;
#pragma unroll
    for (int ds = 0; ds < 4; ++ds) {
        const int d0 = 16 * ds + 4 * g;
        union { f16 x[4]; uint2 u; } H, L;
#pragma unroll
        for (int r = 0; r < 4; ++r) {
            float v = accP[ds][r] * inv + cg * accS[ds][r];
            split2(v, H.x[r], L.x[r]);
        }
        *(uint2*)&aoh[arow + d0] = H.u;
        *(uint2*)&aol[arow + d0] = L.u;
    }
}

// ---------------------------------------------------------------------------
// Kernel 3: out = aout @ Wproj^T + bias (f16-split MFMA). 64x128 tile.
// grid (128, 3), block 256 (waves 2x2 of 32x64).
// ---------------------------------------------------------------------------
__global__ __launch_bounds__(256) void proj_gemm(
    const f16* __restrict__ ah_, const f16* __restrict__ al_,
    const f16* __restrict__ wh, const f16* __restrict__ wl,
    const float* __restrict__ bias, float* __restrict__ out) {
    __shared__ f16 sAh[64 * 32], sAl[64 * 32], sBh[128 * 32], sBl[128 * 32];
    const int tid = threadIdx.x;
    const int w = tid >> 6, lane = tid & 63;
    const int g = lane >> 4, q = lane & 15;
    const int m0 = blockIdx.x * 64, j0 = blockIdx.y * 128;
    const int wm = (w >> 1) * 32, wn = (w & 1) * 64;

    f32x4 acc[2][4];
#pragma unroll
    for (int i = 0; i < 2; ++i)
#pragma unroll
        for (int j = 0; j < 4; ++j) acc[i][j] = (f32x4){0.f, 0.f, 0.f, 0.f};

    for (int ks = 0; ks < 12; ++ks) {
        // staging: waves 0,1 -> A hi/lo (4 instrs); waves 2,3 -> B hi/lo (8)
        if (w < 2) {
            const char* gb = (const char*)(w == 0 ? ah_ : al_) + (size_t)m0 * 768 + ks * 64;
            f16* ld = (w == 0) ? sAh : sAl;
#pragma unroll
            for (int i = 0; i < 4; ++i) {
                const int row = i * 16 + (lane >> 2);
                GLOAD16(gb + (size_t)row * 768 + (((lane & 3) ^ ((row & 6) >> 1)) << 4),
                        ld + i * 512);
            }
        } else {
            const char* gb = (const char*)(w == 2 ? wh : wl) + (size_t)j0 * 768 + ks * 64;
            f16* ld = (w == 2) ? sBh : sBl;
#pragma unroll
            for (int i = 0; i < 8; ++i) {
                const int row = i * 16 + (lane >> 2);
                GLOAD16(gb + (size_t)row * 768 + (((lane & 3) ^ ((row & 6) >> 1)) << 4),
                        ld + i * 512);
            }
        }
        __syncthreads();

        half8 am_h[2], am_l[2], bn_h[4], bn_l[4];
#pragma unroll
        for (int mi = 0; mi < 2; ++mi) {
            const int row = wm + 16 * mi + q;
            const int ch = (g ^ ((row & 6) >> 1)) * 8;
            am_h[mi] = *(const half8*)&sAh[row * 32 + ch];
            am_l[mi] = *(const half8*)&sAl[row * 32 + ch];
        }
#pragma unroll
        for (int nj = 0; nj < 4; ++nj) {
            const int row = wn + 16 * nj + q;
            const int ch = (g ^ ((row & 6) >> 1)) * 8;
            bn_h[nj] = *(const half8*)&sBh[row * 32 + ch];
            bn_l[nj] = *(const half8*)&sBl[row * 32 + ch];
        }
#pragma unroll
        for (int mi = 0; mi < 2; ++mi)
#pragma unroll
            for (int nj = 0; nj < 4; ++nj) {
                acc[mi][nj] = MFMA16(am_h[mi], bn_h[nj], acc[mi][nj]);
                acc[mi][nj] = MFMA16(am_h[mi], bn_l[nj], acc[mi][nj]);
                acc[mi][nj] = MFMA16(am_l[mi], bn_h[nj], acc[mi][nj]);
            }
        __syncthreads();
    }

#pragma unroll
    for (int nj = 0; nj < 4; ++nj) {
        const int jc = j0 + wn + 16 * nj + q;
        const float bb = bias[jc];
#pragma unroll
        for (int mi = 0; mi < 2; ++mi) {
            const int mg = m0 + wm + 16 * mi + 4 * g;
#pragma unroll
            for (int r = 0; r < 4; ++r)
                out[(size_t)(mg + r) * 384 + jc] = acc[mi][nj][r] + bb;
        }
    }
}

// ---------------------------------------------------------------------------
extern "C" void kernel_launch(void* const* d_in, const int* in_sizes, int n_in,
                              void* d_out, int out_size, void* d_ws, size_t ws_size,
                              hipStream_t stream) {
    const float* x     = (const float*)d_in[0];
    const float* Wqkv  = (const float*)d_in[1];
    const float* Wproj = (const float*)d_in[2];
    const float* bproj = (const float*)d_in[3];
    const float* alpha = (const float*)d_in[4];
    float* out = (float*)d_out;

    f16* ws = (f16*)d_ws;
    const size_t XE = 8192 * 384;      // 3,145,728
    const size_t WQ = 1152 * 384;      // 442,368
    const size_t WP = 384 * 384;       // 147,456
    const size_t QE = 48 * 1024 * 64;  // 3,145,728

    f16* xh  = ws;            f16* xl  = xh + XE;
    f16* wqh = xl + XE;       f16* wql = wqh + WQ;
    f16* wph = wql + WQ;      f16* wpl = wph + WP;
    f16* qh  = wpl + WP;      f16* ql  = qh + QE;
    f16* kh  = ql + QE;       f16* kl  = kh + QE;
    f16* vth = kl + QE;       f16* vtl = vth + QE;
    f16* aoh = vtl + QE;      f16* aol = aoh + XE;

    convert_split<<<2048, 256, 0, stream>>>(x, xh, xl, (int)(XE / 4));
    convert_split<<<512, 256, 0, stream>>>(Wqkv, wqh, wql, (int)(WQ / 4));
    convert_split<<<256, 256, 0, stream>>>(Wproj, wph, wpl, (int)(WP / 4));
    qkv_gemm<<<dim3(64, 9), 256, 0, stream>>>(xh, xl, wqh, wql,
                                              qh, ql, kh, kl, vth, vtl);
    attn_mfma<<<dim3(16, 48), 256, 0, stream>>>(qh, ql, kh, kl, vth, vtl,
                                                alpha, aoh, aol);
    proj_gemm<<<dim3(128, 3), 256, 0, stream>>>(aoh, aol, wph, wpl, bproj, out);
}